// Round 4
// 618.261 us; speedup vs baseline: 1.0191x; 1.0191x over previous
//
#include <hip/hip_runtime.h>

// SwitchPolicyValueNetwork — round 3 (3rd resubmit; rounds 1-3 hit GPU-broker /
// container infrastructure failures, kernel never executed).
// vs round 2 (630 us):
//  * expert-weight fp32->bf16 pre-convert kernel (402 MB serial round-trip) DELETED;
//    GEMM2 now always stages B fp32-direct (reg prefetch + f2bf + swizzled ds_write —
//    identical RNE numerics, layout verified against stage128's XOR scheme).
//  * bucketing parallelized: 16 blocks + global device-scope atomics into fixed-stride
//    per-expert row arrays (order-independent), replacing the 1-workgroup serial kernel.
//  * bucket + obs/pre_w/post_w cvts merged into one k_prep launch. 7 -> 5 dispatches.
//  * expert epilogue bias loads hoisted.

#define Bsz 4096
#define INd 1024
#define Hd  2048
#define OUTd 1024
#define NEXP 16

typedef short bf16x8 __attribute__((ext_vector_type(8)));
typedef float f32x4 __attribute__((ext_vector_type(4)));
typedef unsigned short u16;

__device__ __forceinline__ u16 f2bf(float f) {
  unsigned u = __float_as_uint(f);
  u += 0x7FFF + ((u >> 16) & 1);   // RNE
  return (u16)(u >> 16);
}

__device__ __forceinline__ float fast_tanh(float x) {
  float ax = fabsf(x);
  float e = __expf(2.0f * ax);     // inf for large ax -> t -> 1 (safe)
  float t = 1.0f - 2.0f / (e + 1.0f);
  return x < 0.0f ? -t : t;
}

// async 16B global->LDS (direct, no VGPR round-trip)
#define GLL16(g, l)                                                            \
  __builtin_amdgcn_global_load_lds(                                            \
      (const __attribute__((address_space(1))) unsigned int*)(g),              \
      (__attribute__((address_space(3))) unsigned int*)(l), 16, 0, 0)

// ---- staging: 128-row bf16 tile, BK=64 (row = 128B = 8 x 16B chunks) ----
// thread t -> slot (row = t>>3 (+32p), c = t&7); slot c holds global chunk c^(row&7)
// LDS dest = base + (t + 256p)*16 B  (wave-uniform base + lane*16 — required by HW)
__device__ __forceinline__ void stage128(const u16* gbase, int ldk, u16* lds, int t) {
  const int row = t >> 3;
  const int gc8 = ((t & 7) ^ (row & 7)) << 3;
#pragma unroll
  for (int p = 0; p < 4; ++p)
    GLL16(gbase + (size_t)(row + 32 * p) * ldk + gc8, lds + ((t + 256 * p) << 3));
}

__device__ __forceinline__ void stage64(const u16* gbase, int ldk, u16* lds, int t) {
  const int row = t >> 3;
  const int gc8 = ((t & 7) ^ (row & 7)) << 3;
#pragma unroll
  for (int p = 0; p < 2; ++p)
    GLL16(gbase + (size_t)(row + 32 * p) * ldk + gc8, lds + ((t + 256 * p) << 3));
}

// gathered A tile (expert): per-lane global row, tail lanes read a zeroed chunk
__device__ __forceinline__ void stage_gather(const u16* X1k, const int rowg[4],
                                             const u16* zeroc, u16* lds, int t) {
  const int gc8 = ((t & 7) ^ ((t >> 3) & 7)) << 3;
#pragma unroll
  for (int p = 0; p < 4; ++p) {
    const u16* g = (rowg[p] >= 0) ? X1k + (size_t)rowg[p] * Hd + gc8 : zeroc;
    GLL16(g, lds + ((t + 256 * p) << 3));
  }
}

// ---- fp32 128-row tile, register prefetch + convert + swizzled ds_write ----
struct F32Tile { float4 v[8]; };
__device__ __forceinline__ void loadF32tile(const float* W, int ldk, int t, F32Tile& r) {
  const int brow = t & 127, half = t >> 7;
  const float* p = W + (size_t)brow * ldk + (half << 5);
#pragma unroll
  for (int q = 0; q < 8; ++q) r.v[q] = *(const float4*)(p + 4 * q);
}
__device__ __forceinline__ void writeF32tile(const F32Tile& r, u16* lds, int t) {
  const int brow = t & 127, half = t >> 7;
#pragma unroll
  for (int q2 = 0; q2 < 4; ++q2) {
    const float4 x = r.v[2 * q2], y = r.v[2 * q2 + 1];
    bf16x8 o;
    o[0] = (short)f2bf(x.x); o[1] = (short)f2bf(x.y);
    o[2] = (short)f2bf(x.z); o[3] = (short)f2bf(x.w);
    o[4] = (short)f2bf(y.x); o[5] = (short)f2bf(y.y);
    o[6] = (short)f2bf(y.z); o[7] = (short)f2bf(y.w);
    const int gq = (half << 2) + q2;
    const int c = gq ^ (brow & 7);
    *(bf16x8*)&lds[brow * 64 + (c << 3)] = o;
  }
}

// ---- compute one BK=64 tile: 2 k-steps x (MI x 4) MFMAs ----
template <int MI>
__device__ __forceinline__ void compute_tile(const u16* As, const u16* Bs,
                                             int wm, int wn, int fr, int fq,
                                             f32x4 (&acc)[MI][4]) {
#pragma unroll
  for (int ks = 0; ks < 2; ++ks) {
    const int ch = (((ks << 2) + fq) ^ (fr & 7)) << 3;   // swizzled 16B chunk
    bf16x8 af[MI], bq[4];
#pragma unroll
    for (int i = 0; i < MI; ++i) af[i] = *(const bf16x8*)&As[(wm + 16 * i + fr) * 64 + ch];
#pragma unroll
    for (int j = 0; j < 4; ++j) bq[j] = *(const bf16x8*)&Bs[(wn + 16 * j + fr) * 64 + ch];
#pragma unroll
    for (int i = 0; i < MI; ++i)
#pragma unroll
      for (int j = 0; j < 4; ++j)
        acc[i][j] = __builtin_amdgcn_mfma_f32_16x16x32_bf16(af[i], bq[j], acc[i][j], 0, 0, 0);
  }
}

// ---------------- init: zero atomic counters + zero-chunk (ws is poisoned per-iter) ----------------
__global__ __launch_bounds__(64) void k_init(int* __restrict__ cnt, int* __restrict__ zc) {
  int t = threadIdx.x;
  if (t < NEXP) cnt[t] = 0;
  if (t < 16) zc[t] = 0;
}

// ---------------- prep: parallel bucket-scatter + streaming bf16 converts ----------------
// blocks [0,16): bucket 4096 rows via device-scope atomics (row order within a bucket is
//                arbitrary — each row's output is independent, so any order is correct).
// blocks [16, 16+2048): 2 chunks each of {obs:2048, pre_w:1024, post_w:1024} cvt (chunk=2048 elems)
__global__ __launch_bounds__(256) void k_prep(const int* __restrict__ sw,
                                              int* __restrict__ cnt,
                                              int* __restrict__ rows,
                                              const float* __restrict__ obs,  u16* __restrict__ obsb,
                                              const float* __restrict__ prew, u16* __restrict__ prewb,
                                              const float* __restrict__ pw,   u16* __restrict__ postwb,
                                              int docvt) {
  const int bid = blockIdx.x, tid = threadIdx.x;
  if (bid < 16) {
    const int r = bid * 256 + tid;
    const int e = sw[r];
    const int p = atomicAdd(&cnt[e], 1);   // device-scope by default on CDNA
    rows[e * Bsz + p] = r;
    return;
  }
  if (!docvt) return;
  const int c0 = bid - 16;
#pragma unroll
  for (int q = 0; q < 2; ++q) {
    const int c = c0 + q * 2048;           // c in [0,4096)
    const float* src; u16* dst;
    if (c < 2048)      { src = obs  + (size_t)c * 2048;          dst = obsb   + (size_t)c * 2048; }
    else if (c < 3072) { src = prew + (size_t)(c - 2048) * 2048; dst = prewb  + (size_t)(c - 2048) * 2048; }
    else               { src = pw   + (size_t)(c - 3072) * 2048; dst = postwb + (size_t)(c - 3072) * 2048; }
    const int i = tid * 8;
    float4 a = *(const float4*)(src + i);
    float4 b = *(const float4*)(src + i + 4);
    bf16x8 o;
    o[0] = (short)f2bf(a.x); o[1] = (short)f2bf(a.y);
    o[2] = (short)f2bf(a.z); o[3] = (short)f2bf(a.w);
    o[4] = (short)f2bf(b.x); o[5] = (short)f2bf(b.y);
    o[6] = (short)f2bf(b.z); o[7] = (short)f2bf(b.w);
    *(bf16x8*)(dst + i) = o;
  }
}

// ---------------- GEMM1: X1 = tanh(obs @ pre_w^T + pre_b) ----------------
template <bool PC>
__global__ __launch_bounds__(256) void k_pre_t(const float* __restrict__ obs32,
                                               const u16* __restrict__ obsb,
                                               const float* __restrict__ prew32,
                                               const u16* __restrict__ prewb,
                                               const float* __restrict__ pre_b,
                                               u16* __restrict__ X1) {
  __shared__ u16 As[2][128 * 64];
  __shared__ u16 Bs[2][128 * 64];
  const int tid = threadIdx.x, lane = tid & 63, wv = tid >> 6;
  const int wm = (wv >> 1) << 6, wn = (wv & 1) << 6;
  const int fr = lane & 15, fq = lane >> 4;
  const int n0 = blockIdx.x * 128, m0 = blockIdx.y * 128;
  f32x4 acc[4][4] = {};
  const int NT = INd / 64;

  if constexpr (PC) {
    stage128(obsb + (size_t)m0 * INd, INd, As[0], tid);
    stage128(prewb + (size_t)n0 * INd, INd, Bs[0], tid);
    __syncthreads();
    for (int kt = 0; kt < NT; ++kt) {
      const int nb = (kt + 1) & 1;
      if (kt + 1 < NT) {
        stage128(obsb + (size_t)m0 * INd + (kt + 1) * 64, INd, As[nb], tid);
        stage128(prewb + (size_t)n0 * INd + (kt + 1) * 64, INd, Bs[nb], tid);
      }
      compute_tile<4>(As[kt & 1], Bs[kt & 1], wm, wn, fr, fq, acc);
      __syncthreads();
    }
  } else {
    F32Tile ra, rb;
    loadF32tile(obs32 + (size_t)m0 * INd, INd, tid, ra);
    loadF32tile(prew32 + (size_t)n0 * INd, INd, tid, rb);
    writeF32tile(ra, As[0], tid);
    writeF32tile(rb, Bs[0], tid);
    __syncthreads();
    for (int kt = 0; kt < NT; ++kt) {
      const int nb = (kt + 1) & 1;
      const bool more = (kt + 1) < NT;
      F32Tile na, nbv;
      if (more) {
        loadF32tile(obs32 + (size_t)m0 * INd + (kt + 1) * 64, INd, tid, na);
        loadF32tile(prew32 + (size_t)n0 * INd + (kt + 1) * 64, INd, tid, nbv);
      }
      compute_tile<4>(As[kt & 1], Bs[kt & 1], wm, wn, fr, fq, acc);
      if (more) { writeF32tile(na, As[nb], tid); writeF32tile(nbv, Bs[nb], tid); }
      __syncthreads();
    }
  }

#pragma unroll
  for (int j = 0; j < 4; ++j) {
    int col = n0 + wn + 16 * j + fr;
    float bias = pre_b[col];
#pragma unroll
    for (int i = 0; i < 4; ++i) {
      int rb2 = m0 + wm + 16 * i + fq * 4;
#pragma unroll
      for (int r = 0; r < 4; ++r)
        X1[(size_t)(rb2 + r) * Hd + col] = f2bf(fast_tanh(acc[i][j][r] + bias));
    }
  }
}

// ------- GEMM2 (grouped): Z[row] = tanh(X1[row] @ W_e^T + b_e) -------
// B staged fp32-direct (reg prefetch + convert) — no ewb pre-pass. Expert weight
// panels dedup in L2/L3 across the co-resident block cohort (~268 MB unique HBM).
__global__ __launch_bounds__(256) void k_expert(const u16* __restrict__ X1,
                                                const float* __restrict__ ew32,
                                                const float* __restrict__ eb,
                                                const int* __restrict__ cnt,
                                                const int* __restrict__ rows,
                                                const u16* __restrict__ zeroc,
                                                u16* __restrict__ Z) {
  const int e = blockIdx.y >> 5, rt = blockIdx.y & 31;
  const int ce = cnt[e];
  const int tbase = rt * 128;
  if (tbase >= ce) return;                  // block-uniform early exit
  const int nval = min(128, ce - tbase);
  const int n0 = blockIdx.x * 128;
  const int* rowsE = rows + e * Bsz + tbase;

  __shared__ u16 As[2][128 * 64];
  __shared__ u16 Bs[2][128 * 64];
  const int tid = threadIdx.x, lane = tid & 63, wv = tid >> 6;
  const int wm = (wv >> 1) << 6, wn = (wv & 1) << 6;
  const int fr = lane & 15, fq = lane >> 4;

  int rowg[4];
  {
    const int r0 = tid >> 3;
#pragma unroll
    for (int p = 0; p < 4; ++p) {
      int ar = r0 + 32 * p;
      rowg[p] = (ar < nval) ? rowsE[ar] : -1;
    }
  }
  f32x4 acc[4][4] = {};
  const int NT = Hd / 64;

  const float* We32 = ew32 + (size_t)e * Hd * Hd + (size_t)n0 * Hd;
  stage_gather(X1, rowg, zeroc, As[0], tid);
  {
    F32Tile rb;
    loadF32tile(We32, Hd, tid, rb);
    writeF32tile(rb, Bs[0], tid);
  }
  __syncthreads();
  for (int kt = 0; kt < NT; ++kt) {
    const int nb = (kt + 1) & 1;
    const bool more = (kt + 1) < NT;
    F32Tile rn;
    if (more) {
      stage_gather(X1 + (kt + 1) * 64, rowg, zeroc, As[nb], tid);
      loadF32tile(We32 + (kt + 1) * 64, Hd, tid, rn);
    }
    compute_tile<4>(As[kt & 1], Bs[kt & 1], wm, wn, fr, fq, acc);
    if (more) writeF32tile(rn, Bs[nb], tid);
    __syncthreads();
  }

  float bias[4];
#pragma unroll
  for (int j = 0; j < 4; ++j) bias[j] = eb[(size_t)e * Hd + n0 + wn + 16 * j + fr];

#pragma unroll
  for (int i = 0; i < 4; ++i) {
#pragma unroll
    for (int r = 0; r < 4; ++r) {
      int arow = wm + 16 * i + fq * 4 + r;
      if (arow < nval) {
        int orow = rowsE[arow];
#pragma unroll
        for (int j = 0; j < 4; ++j) {
          int col = n0 + wn + 16 * j + fr;
          Z[(size_t)orow * Hd + col] = f2bf(fast_tanh(acc[i][j][r] + bias[j]));
        }
      }
    }
  }
}

// ---------------- GEMM3: out = tanh(Z @ post_w^T + post_b), BM=64 ----------------
template <bool PC>
__global__ __launch_bounds__(256) void k_post_t(const u16* __restrict__ Z,
                                                const float* __restrict__ pw32,
                                                const u16* __restrict__ pwb,
                                                const float* __restrict__ pb,
                                                float* __restrict__ out) {
  __shared__ u16 As[2][64 * 64];
  __shared__ u16 Bs[2][128 * 64];
  const int tid = threadIdx.x, lane = tid & 63, wv = tid >> 6;
  const int wm = (wv >> 1) << 5, wn = (wv & 1) << 6;   // wave tile 32x64
  const int fr = lane & 15, fq = lane >> 4;
  const int n0 = blockIdx.x * 128, m0 = blockIdx.y * 64;
  f32x4 acc[2][4] = {};
  const int NT = Hd / 64;

  if constexpr (PC) {
    stage64(Z + (size_t)m0 * Hd, Hd, As[0], tid);
    stage128(pwb + (size_t)n0 * Hd, Hd, Bs[0], tid);
    __syncthreads();
    for (int kt = 0; kt < NT; ++kt) {
      const int nb = (kt + 1) & 1;
      if (kt + 1 < NT) {
        stage64(Z + (size_t)m0 * Hd + (kt + 1) * 64, Hd, As[nb], tid);
        stage128(pwb + (size_t)n0 * Hd + (kt + 1) * 64, Hd, Bs[nb], tid);
      }
      compute_tile<2>(As[kt & 1], Bs[kt & 1], wm, wn, fr, fq, acc);
      __syncthreads();
    }
  } else {
    stage64(Z + (size_t)m0 * Hd, Hd, As[0], tid);
    {
      F32Tile rb;
      loadF32tile(pw32 + (size_t)n0 * Hd, Hd, tid, rb);
      writeF32tile(rb, Bs[0], tid);
    }
    __syncthreads();
    for (int kt = 0; kt < NT; ++kt) {
      const int nb = (kt + 1) & 1;
      const bool more = (kt + 1) < NT;
      F32Tile rn;
      if (more) {
        stage64(Z + (size_t)m0 * Hd + (kt + 1) * 64, Hd, As[nb], tid);
        loadF32tile(pw32 + (size_t)n0 * Hd + (kt + 1) * 64, Hd, tid, rn);
      }
      compute_tile<2>(As[kt & 1], Bs[kt & 1], wm, wn, fr, fq, acc);
      if (more) writeF32tile(rn, Bs[nb], tid);
      __syncthreads();
    }
  }

#pragma unroll
  for (int j = 0; j < 4; ++j) {
    int col = n0 + wn + 16 * j + fr;
    float bias = pb[col];
#pragma unroll
    for (int i = 0; i < 2; ++i) {
      int rb2 = m0 + wm + 16 * i + fq * 4;
#pragma unroll
      for (int r = 0; r < 4; ++r)
        out[(size_t)(rb2 + r) * OUTd + col] = fast_tanh(acc[i][j][r] + bias);
    }
  }
}

extern "C" void kernel_launch(void* const* d_in, const int* in_sizes, int n_in,
                              void* d_out, int out_size, void* d_ws, size_t ws_size,
                              hipStream_t stream) {
  const float* obs   = (const float*)d_in[0];
  const int*   sw    = (const int*)d_in[1];
  const float* pre_w = (const float*)d_in[2];
  const float* pre_b = (const float*)d_in[3];
  const float* ew    = (const float*)d_in[4];
  const float* eb    = (const float*)d_in[5];
  const float* pw    = (const float*)d_in[6];
  const float* pb    = (const float*)d_in[7];
  float* out = (float*)d_out;

  // ws layout:
  //   [0,64)        cnt[16] (atomic bucket counters)
  //   [256,288)     zero chunk (16B used)
  //   [4096,266240) rows[16][4096]
  //   1MB+0         X1    (16 MB bf16)
  //   1MB+16MB      Zb    (16 MB bf16)
  //   1MB+32MB      obsb  (8 MB)
  //   1MB+40MB      prewb (4 MB)
  //   1MB+44MB      postwb(4 MB)   -> need 49 MB for the precvt tier
  char* ws = (char*)d_ws;
  int* cnt  = (int*)ws;
  int* zc   = (int*)(ws + 256);
  int* rows = (int*)(ws + 4096);
  const size_t M1 = (size_t)1 << 20;
  u16* X1     = (u16*)(ws + M1);
  u16* Zb     = (u16*)(ws + M1 + ((size_t)16 << 20));
  u16* obsb   = (u16*)(ws + M1 + ((size_t)32 << 20));
  u16* prewb  = (u16*)(ws + M1 + ((size_t)40 << 20));
  u16* postwb = (u16*)(ws + M1 + ((size_t)44 << 20));
  const bool pc = ws_size >= M1 + ((size_t)48 << 20);

  k_init<<<dim3(1), dim3(64), 0, stream>>>(cnt, zc);

  k_prep<<<dim3(pc ? 2064 : 16), dim3(256), 0, stream>>>(
      sw, cnt, rows, obs, obsb, pre_w, prewb, pw, postwb, pc ? 1 : 0);

  if (pc)
    k_pre_t<true><<<dim3(Hd / 128, Bsz / 128), dim3(256), 0, stream>>>(obs, obsb, pre_w, prewb, pre_b, X1);
  else
    k_pre_t<false><<<dim3(Hd / 128, Bsz / 128), dim3(256), 0, stream>>>(obs, obsb, pre_w, prewb, pre_b, X1);

  k_expert<<<dim3(Hd / 128, NEXP * 32), dim3(256), 0, stream>>>(X1, ew, eb, cnt, rows, (const u16*)zc, Zb);

  if (pc)
    k_post_t<true><<<dim3(OUTd / 128, Bsz / 64), dim3(256), 0, stream>>>(Zb, pw, postwb, pb, out);
  else
    k_post_t<false><<<dim3(OUTd / 128, Bsz / 64), dim3(256), 0, stream>>>(Zb, pw, postwb, pb, out);
}

// Round 5
// 544.383 us; speedup vs baseline: 1.1574x; 1.1357x over previous
//
#include <hip/hip_runtime.h>

// SwitchPolicyValueNetwork — round 4.
// vs round 3 (618 us; k_expert = 247 us, MfmaUtil 7%, HBM 13%, Occ 13% => latency-bound):
//  * k_expert B fp32 staging COALESCED: old map was row-per-lane (8KB stride, 64
//    16B-segments per instruction). New map: 16 lanes cover one row's 256B
//    contiguously (4 segments/inst). Same XOR-swizzled LDS chunk layout.
//  * k_expert tile 128x128 -> 128x64 (BN=64): active blocks 512 -> ~1024,
//    LDS 64KB -> 48KB => 3 resident blocks/CU (was 2), 12 waves/CU.
//  * everything else (k_prep/k_pre/k_post) unchanged — no counter evidence on them.

#define Bsz 4096
#define INd 1024
#define Hd  2048
#define OUTd 1024
#define NEXP 16

typedef short bf16x8 __attribute__((ext_vector_type(8)));
typedef float f32x4 __attribute__((ext_vector_type(4)));
typedef unsigned short u16;

__device__ __forceinline__ u16 f2bf(float f) {
  unsigned u = __float_as_uint(f);
  u += 0x7FFF + ((u >> 16) & 1);   // RNE
  return (u16)(u >> 16);
}

__device__ __forceinline__ float fast_tanh(float x) {
  float ax = fabsf(x);
  float e = __expf(2.0f * ax);     // inf for large ax -> t -> 1 (safe)
  float t = 1.0f - 2.0f / (e + 1.0f);
  return x < 0.0f ? -t : t;
}

// async 16B global->LDS (direct, no VGPR round-trip)
#define GLL16(g, l)                                                            \
  __builtin_amdgcn_global_load_lds(                                            \
      (const __attribute__((address_space(1))) unsigned int*)(g),              \
      (__attribute__((address_space(3))) unsigned int*)(l), 16, 0, 0)

// ---- staging: 128-row bf16 tile, BK=64 (row = 128B = 8 x 16B chunks) ----
// thread t -> slot (row = t>>3 (+32p), c = t&7); slot c holds global chunk c^(row&7)
// LDS dest = base + (t + 256p)*16 B  (wave-uniform base + lane*16 — required by HW)
__device__ __forceinline__ void stage128(const u16* gbase, int ldk, u16* lds, int t) {
  const int row = t >> 3;
  const int gc8 = ((t & 7) ^ (row & 7)) << 3;
#pragma unroll
  for (int p = 0; p < 4; ++p)
    GLL16(gbase + (size_t)(row + 32 * p) * ldk + gc8, lds + ((t + 256 * p) << 3));
}

__device__ __forceinline__ void stage64(const u16* gbase, int ldk, u16* lds, int t) {
  const int row = t >> 3;
  const int gc8 = ((t & 7) ^ (row & 7)) << 3;
#pragma unroll
  for (int p = 0; p < 2; ++p)
    GLL16(gbase + (size_t)(row + 32 * p) * ldk + gc8, lds + ((t + 256 * p) << 3));
}

// gathered A tile (expert): per-lane global row, tail lanes read a zeroed chunk
__device__ __forceinline__ void stage_gather(const u16* X1k, const int rowg[4],
                                             const u16* zeroc, u16* lds, int t) {
  const int gc8 = ((t & 7) ^ ((t >> 3) & 7)) << 3;
#pragma unroll
  for (int p = 0; p < 4; ++p) {
    const u16* g = (rowg[p] >= 0) ? X1k + (size_t)rowg[p] * Hd + gc8 : zeroc;
    GLL16(g, lds + ((t + 256 * p) << 3));
  }
}

// ---- fp32 128-row tile (legacy map, used by non-PC fallback paths only) ----
struct F32Tile { float4 v[8]; };
__device__ __forceinline__ void loadF32tile(const float* W, int ldk, int t, F32Tile& r) {
  const int brow = t & 127, half = t >> 7;
  const float* p = W + (size_t)brow * ldk + (half << 5);
#pragma unroll
  for (int q = 0; q < 8; ++q) r.v[q] = *(const float4*)(p + 4 * q);
}
__device__ __forceinline__ void writeF32tile(const F32Tile& r, u16* lds, int t) {
  const int brow = t & 127, half = t >> 7;
#pragma unroll
  for (int q2 = 0; q2 < 4; ++q2) {
    const float4 x = r.v[2 * q2], y = r.v[2 * q2 + 1];
    bf16x8 o;
    o[0] = (short)f2bf(x.x); o[1] = (short)f2bf(x.y);
    o[2] = (short)f2bf(x.z); o[3] = (short)f2bf(x.w);
    o[4] = (short)f2bf(y.x); o[5] = (short)f2bf(y.y);
    o[6] = (short)f2bf(y.z); o[7] = (short)f2bf(y.w);
    const int gq = (half << 2) + q2;
    const int c = gq ^ (brow & 7);
    *(bf16x8*)&lds[brow * 64 + (c << 3)] = o;
  }
}

// ---- fp32 64-row tile, COALESCED: 16 lanes span one row's 64 floats (256B
// contiguous per row, 4 rows per wave-instruction). Each thread owns fp32 cols
// [4*(t&15), +4) of rows (t>>4)+16q -> 4 bf16 = 8B = half a 16B chunk.
// LDS layout identical to stage128's: row-major [64][64] bf16, 16B chunk c
// stored at c ^ (row&7). row&7 == (t>>4)&7 (16q = 0 mod 8) — per-thread const.
struct F32TileB64 { float4 v[4]; };
__device__ __forceinline__ void loadF32B64(const float* W, int ldk, int t, F32TileB64& r) {
  const int r0 = t >> 4;               // 0..15
  const int c4 = (t & 15) << 2;        // fp32 col base
#pragma unroll
  for (int q = 0; q < 4; ++q)
    r.v[q] = *(const float4*)(W + (size_t)(r0 + 16 * q) * ldk + c4);
}
__device__ __forceinline__ void writeF32B64(const F32TileB64& r, u16* lds, int t) {
  const int c16 = (t & 15) >> 1;       // 16B chunk index 0..7
  const int half = t & 1;              // 8B half within chunk
  const int swz = (t >> 4) & 7;        // == row&7 for all q
  const int coff = ((c16 ^ swz) << 3) + (half << 2);   // u16 offset in row
#pragma unroll
  for (int q = 0; q < 4; ++q) {
    const int row = (t >> 4) + 16 * q;
    const float4 x = r.v[q];
    unsigned long long pk =
        (unsigned long long)f2bf(x.x) | ((unsigned long long)f2bf(x.y) << 16) |
        ((unsigned long long)f2bf(x.z) << 32) | ((unsigned long long)f2bf(x.w) << 48);
    *(unsigned long long*)&lds[row * 64 + coff] = pk;
  }
}

// ---- compute one BK=64 tile: 2 k-steps x (MI x NJ) MFMAs ----
template <int MI, int NJ>
__device__ __forceinline__ void compute_tile(const u16* As, const u16* Bs,
                                             int wm, int wn, int fr, int fq,
                                             f32x4 (&acc)[MI][NJ]) {
#pragma unroll
  for (int ks = 0; ks < 2; ++ks) {
    const int ch = (((ks << 2) + fq) ^ (fr & 7)) << 3;   // swizzled 16B chunk
    bf16x8 af[MI], bq[NJ];
#pragma unroll
    for (int i = 0; i < MI; ++i) af[i] = *(const bf16x8*)&As[(wm + 16 * i + fr) * 64 + ch];
#pragma unroll
    for (int j = 0; j < NJ; ++j) bq[j] = *(const bf16x8*)&Bs[(wn + 16 * j + fr) * 64 + ch];
#pragma unroll
    for (int i = 0; i < MI; ++i)
#pragma unroll
      for (int j = 0; j < NJ; ++j)
        acc[i][j] = __builtin_amdgcn_mfma_f32_16x16x32_bf16(af[i], bq[j], acc[i][j], 0, 0, 0);
  }
}

// ---------------- init: zero atomic counters + zero-chunk (ws is poisoned per-iter) ----------------
__global__ __launch_bounds__(64) void k_init(int* __restrict__ cnt, int* __restrict__ zc) {
  int t = threadIdx.x;
  if (t < NEXP) cnt[t] = 0;
  if (t < 16) zc[t] = 0;
}

// ---------------- prep: parallel bucket-scatter + streaming bf16 converts ----------------
__global__ __launch_bounds__(256) void k_prep(const int* __restrict__ sw,
                                              int* __restrict__ cnt,
                                              int* __restrict__ rows,
                                              const float* __restrict__ obs,  u16* __restrict__ obsb,
                                              const float* __restrict__ prew, u16* __restrict__ prewb,
                                              const float* __restrict__ pw,   u16* __restrict__ postwb,
                                              int docvt) {
  const int bid = blockIdx.x, tid = threadIdx.x;
  if (bid < 16) {
    const int r = bid * 256 + tid;
    const int e = sw[r];
    const int p = atomicAdd(&cnt[e], 1);   // device-scope by default on CDNA
    rows[e * Bsz + p] = r;
    return;
  }
  if (!docvt) return;
  const int c0 = bid - 16;
#pragma unroll
  for (int q = 0; q < 2; ++q) {
    const int c = c0 + q * 2048;           // c in [0,4096)
    const float* src; u16* dst;
    if (c < 2048)      { src = obs  + (size_t)c * 2048;          dst = obsb   + (size_t)c * 2048; }
    else if (c < 3072) { src = prew + (size_t)(c - 2048) * 2048; dst = prewb  + (size_t)(c - 2048) * 2048; }
    else               { src = pw   + (size_t)(c - 3072) * 2048; dst = postwb + (size_t)(c - 3072) * 2048; }
    const int i = tid * 8;
    float4 a = *(const float4*)(src + i);
    float4 b = *(const float4*)(src + i + 4);
    bf16x8 o;
    o[0] = (short)f2bf(a.x); o[1] = (short)f2bf(a.y);
    o[2] = (short)f2bf(a.z); o[3] = (short)f2bf(a.w);
    o[4] = (short)f2bf(b.x); o[5] = (short)f2bf(b.y);
    o[6] = (short)f2bf(b.z); o[7] = (short)f2bf(b.w);
    *(bf16x8*)(dst + i) = o;
  }
}

// ---------------- GEMM1: X1 = tanh(obs @ pre_w^T + pre_b) ----------------
template <bool PC>
__global__ __launch_bounds__(256) void k_pre_t(const float* __restrict__ obs32,
                                               const u16* __restrict__ obsb,
                                               const float* __restrict__ prew32,
                                               const u16* __restrict__ prewb,
                                               const float* __restrict__ pre_b,
                                               u16* __restrict__ X1) {
  __shared__ u16 As[2][128 * 64];
  __shared__ u16 Bs[2][128 * 64];
  const int tid = threadIdx.x, lane = tid & 63, wv = tid >> 6;
  const int wm = (wv >> 1) << 6, wn = (wv & 1) << 6;
  const int fr = lane & 15, fq = lane >> 4;
  const int n0 = blockIdx.x * 128, m0 = blockIdx.y * 128;
  f32x4 acc[4][4] = {};
  const int NT = INd / 64;

  if constexpr (PC) {
    stage128(obsb + (size_t)m0 * INd, INd, As[0], tid);
    stage128(prewb + (size_t)n0 * INd, INd, Bs[0], tid);
    __syncthreads();
    for (int kt = 0; kt < NT; ++kt) {
      const int nb = (kt + 1) & 1;
      if (kt + 1 < NT) {
        stage128(obsb + (size_t)m0 * INd + (kt + 1) * 64, INd, As[nb], tid);
        stage128(prewb + (size_t)n0 * INd + (kt + 1) * 64, INd, Bs[nb], tid);
      }
      compute_tile<4, 4>(As[kt & 1], Bs[kt & 1], wm, wn, fr, fq, acc);
      __syncthreads();
    }
  } else {
    F32Tile ra, rb;
    loadF32tile(obs32 + (size_t)m0 * INd, INd, tid, ra);
    loadF32tile(prew32 + (size_t)n0 * INd, INd, tid, rb);
    writeF32tile(ra, As[0], tid);
    writeF32tile(rb, Bs[0], tid);
    __syncthreads();
    for (int kt = 0; kt < NT; ++kt) {
      const int nb = (kt + 1) & 1;
      const bool more = (kt + 1) < NT;
      F32Tile na, nbv;
      if (more) {
        loadF32tile(obs32 + (size_t)m0 * INd + (kt + 1) * 64, INd, tid, na);
        loadF32tile(prew32 + (size_t)n0 * INd + (kt + 1) * 64, INd, tid, nbv);
      }
      compute_tile<4, 4>(As[kt & 1], Bs[kt & 1], wm, wn, fr, fq, acc);
      if (more) { writeF32tile(na, As[nb], tid); writeF32tile(nbv, Bs[nb], tid); }
      __syncthreads();
    }
  }

#pragma unroll
  for (int j = 0; j < 4; ++j) {
    int col = n0 + wn + 16 * j + fr;
    float bias = pre_b[col];
#pragma unroll
    for (int i = 0; i < 4; ++i) {
      int rb2 = m0 + wm + 16 * i + fq * 4;
#pragma unroll
      for (int r = 0; r < 4; ++r)
        X1[(size_t)(rb2 + r) * Hd + col] = f2bf(fast_tanh(acc[i][j][r] + bias));
    }
  }
}

// ------- GEMM2 (grouped): Z[row] = tanh(X1[row] @ W_e^T + b_e) -------
// Tile 128x64 (BN=64): ~1024 active blocks, 48KB LDS -> 3 resident blocks/CU.
// B staged fp32-direct with the coalesced 16-lanes-per-row map.
__global__ __launch_bounds__(256) void k_expert(const u16* __restrict__ X1,
                                                const float* __restrict__ ew32,
                                                const float* __restrict__ eb,
                                                const int* __restrict__ cnt,
                                                const int* __restrict__ rows,
                                                const u16* __restrict__ zeroc,
                                                u16* __restrict__ Z) {
  const int e = blockIdx.y >> 5, rt = blockIdx.y & 31;
  const int ce = cnt[e];
  const int tbase = rt * 128;
  if (tbase >= ce) return;                  // block-uniform early exit
  const int nval = min(128, ce - tbase);
  const int n0 = blockIdx.x * 64;
  const int* rowsE = rows + e * Bsz + tbase;

  __shared__ u16 As[2][128 * 64];           // 32 KB
  __shared__ u16 Bs[2][64 * 64];            // 16 KB
  const int tid = threadIdx.x, lane = tid & 63, wv = tid >> 6;
  const int wm = (wv >> 1) << 6, wn = (wv & 1) << 5;   // wave tile 64x32
  const int fr = lane & 15, fq = lane >> 4;

  int rowg[4];
  {
    const int r0 = tid >> 3;
#pragma unroll
    for (int p = 0; p < 4; ++p) {
      int ar = r0 + 32 * p;
      rowg[p] = (ar < nval) ? rowsE[ar] : -1;
    }
  }
  f32x4 acc[4][2] = {};
  const int NT = Hd / 64;

  const float* We32 = ew32 + (size_t)e * Hd * Hd + (size_t)n0 * Hd;
  stage_gather(X1, rowg, zeroc, As[0], tid);
  {
    F32TileB64 rb;
    loadF32B64(We32, Hd, tid, rb);
    writeF32B64(rb, Bs[0], tid);
  }
  __syncthreads();
  for (int kt = 0; kt < NT; ++kt) {
    const int nb = (kt + 1) & 1;
    const bool more = (kt + 1) < NT;
    F32TileB64 rn;
    if (more) {
      stage_gather(X1 + (kt + 1) * 64, rowg, zeroc, As[nb], tid);
      loadF32B64(We32 + (kt + 1) * 64, Hd, tid, rn);
    }
    compute_tile<4, 2>(As[kt & 1], Bs[kt & 1], wm, wn, fr, fq, acc);
    if (more) writeF32B64(rn, Bs[nb], tid);
    __syncthreads();
  }

  float bias[2];
#pragma unroll
  for (int j = 0; j < 2; ++j) bias[j] = eb[(size_t)e * Hd + n0 + wn + 16 * j + fr];

#pragma unroll
  for (int i = 0; i < 4; ++i) {
#pragma unroll
    for (int r = 0; r < 4; ++r) {
      int arow = wm + 16 * i + fq * 4 + r;
      if (arow < nval) {
        int orow = rowsE[arow];
#pragma unroll
        for (int j = 0; j < 2; ++j) {
          int col = n0 + wn + 16 * j + fr;
          Z[(size_t)orow * Hd + col] = f2bf(fast_tanh(acc[i][j][r] + bias[j]));
        }
      }
    }
  }
}

// ---------------- GEMM3: out = tanh(Z @ post_w^T + post_b), BM=64 ----------------
template <bool PC>
__global__ __launch_bounds__(256) void k_post_t(const u16* __restrict__ Z,
                                                const float* __restrict__ pw32,
                                                const u16* __restrict__ pwb,
                                                const float* __restrict__ pb,
                                                float* __restrict__ out) {
  __shared__ u16 As[2][64 * 64];
  __shared__ u16 Bs[2][128 * 64];
  const int tid = threadIdx.x, lane = tid & 63, wv = tid >> 6;
  const int wm = (wv >> 1) << 5, wn = (wv & 1) << 6;   // wave tile 32x64
  const int fr = lane & 15, fq = lane >> 4;
  const int n0 = blockIdx.x * 128, m0 = blockIdx.y * 64;
  f32x4 acc[2][4] = {};
  const int NT = Hd / 64;

  if constexpr (PC) {
    stage64(Z + (size_t)m0 * Hd, Hd, As[0], tid);
    stage128(pwb + (size_t)n0 * Hd, Hd, Bs[0], tid);
    __syncthreads();
    for (int kt = 0; kt < NT; ++kt) {
      const int nb = (kt + 1) & 1;
      if (kt + 1 < NT) {
        stage64(Z + (size_t)m0 * Hd + (kt + 1) * 64, Hd, As[nb], tid);
        stage128(pwb + (size_t)n0 * Hd + (kt + 1) * 64, Hd, Bs[nb], tid);
      }
      compute_tile<2, 4>(As[kt & 1], Bs[kt & 1], wm, wn, fr, fq, acc);
      __syncthreads();
    }
  } else {
    stage64(Z + (size_t)m0 * Hd, Hd, As[0], tid);
    {
      F32Tile rb;
      loadF32tile(pw32 + (size_t)n0 * Hd, Hd, tid, rb);
      writeF32tile(rb, Bs[0], tid);
    }
    __syncthreads();
    for (int kt = 0; kt < NT; ++kt) {
      const int nb = (kt + 1) & 1;
      const bool more = (kt + 1) < NT;
      F32Tile rn;
      if (more) {
        stage64(Z + (size_t)m0 * Hd + (kt + 1) * 64, Hd, As[nb], tid);
        loadF32tile(pw32 + (size_t)n0 * Hd + (kt + 1) * 64, Hd, tid, rn);
      }
      compute_tile<2, 4>(As[kt & 1], Bs[kt & 1], wm, wn, fr, fq, acc);
      if (more) writeF32tile(rn, Bs[nb], tid);
      __syncthreads();
    }
  }

#pragma unroll
  for (int j = 0; j < 4; ++j) {
    int col = n0 + wn + 16 * j + fr;
    float bias = pb[col];
#pragma unroll
    for (int i = 0; i < 2; ++i) {
      int rb2 = m0 + wm + 16 * i + fq * 4;
#pragma unroll
      for (int r = 0; r < 4; ++r)
        out[(size_t)(rb2 + r) * OUTd + col] = fast_tanh(acc[i][j][r] + bias);
    }
  }
}

extern "C" void kernel_launch(void* const* d_in, const int* in_sizes, int n_in,
                              void* d_out, int out_size, void* d_ws, size_t ws_size,
                              hipStream_t stream) {
  const float* obs   = (const float*)d_in[0];
  const int*   sw    = (const int*)d_in[1];
  const float* pre_w = (const float*)d_in[2];
  const float* pre_b = (const float*)d_in[3];
  const float* ew    = (const float*)d_in[4];
  const float* eb    = (const float*)d_in[5];
  const float* pw    = (const float*)d_in[6];
  const float* pb    = (const float*)d_in[7];
  float* out = (float*)d_out;

  // ws layout:
  //   [0,64)        cnt[16] (atomic bucket counters)
  //   [256,288)     zero chunk (16B used)
  //   [4096,266240) rows[16][4096]
  //   1MB+0         X1    (16 MB bf16)
  //   1MB+16MB      Zb    (16 MB bf16)
  //   1MB+32MB      obsb  (8 MB)
  //   1MB+40MB      prewb (4 MB)
  //   1MB+44MB      postwb(4 MB)   -> need 49 MB for the precvt tier
  char* ws = (char*)d_ws;
  int* cnt  = (int*)ws;
  int* zc   = (int*)(ws + 256);
  int* rows = (int*)(ws + 4096);
  const size_t M1 = (size_t)1 << 20;
  u16* X1     = (u16*)(ws + M1);
  u16* Zb     = (u16*)(ws + M1 + ((size_t)16 << 20));
  u16* obsb   = (u16*)(ws + M1 + ((size_t)32 << 20));
  u16* prewb  = (u16*)(ws + M1 + ((size_t)40 << 20));
  u16* postwb = (u16*)(ws + M1 + ((size_t)44 << 20));
  const bool pc = ws_size >= M1 + ((size_t)48 << 20);

  k_init<<<dim3(1), dim3(64), 0, stream>>>(cnt, zc);

  k_prep<<<dim3(pc ? 2064 : 16), dim3(256), 0, stream>>>(
      sw, cnt, rows, obs, obsb, pre_w, prewb, pw, postwb, pc ? 1 : 0);

  if (pc)
    k_pre_t<true><<<dim3(Hd / 128, Bsz / 128), dim3(256), 0, stream>>>(obs, obsb, pre_w, prewb, pre_b, X1);
  else
    k_pre_t<false><<<dim3(Hd / 128, Bsz / 128), dim3(256), 0, stream>>>(obs, obsb, pre_w, prewb, pre_b, X1);

  k_expert<<<dim3(Hd / 64, NEXP * 32), dim3(256), 0, stream>>>(X1, ew, eb, cnt, rows, (const u16*)zc, Zb);

  if (pc)
    k_post_t<true><<<dim3(OUTd / 128, Bsz / 64), dim3(256), 0, stream>>>(Zb, pw, postwb, pb, out);
  else
    k_post_t<false><<<dim3(OUTd / 128, Bsz / 64), dim3(256), 0, stream>>>(Zb, pw, postwb, pb, out);
}